// Round 1
// baseline (87057.727 us; speedup 1.0000x reference)
//
#include <hip/hip_runtime.h>
#include <hip/hip_cooperative_groups.h>
#include <math.h>

namespace cg = cooperative_groups;

// Problem constants (match reference)
constexpr int EMBD  = 512;
constexpr int HID   = 1024;
constexpr int NOUT  = 5;
constexpr int SEQ   = 512;
constexpr int BATCH = 64;
constexpr int G3    = 3 * HID;   // 3072

// ---------------------------------------------------------------------------
// Prep: transpose W [K, C] (row-major) -> WT [C, K] so the per-thread K-loop
// reads are contiguous float4. One-time ~19 MB, trivial cost.
// ---------------------------------------------------------------------------
__global__ __launch_bounds__(256) void transpose_w(const float* __restrict__ W,
                                                   float* __restrict__ WT,
                                                   int K, int C) {
    int idx = blockIdx.x * 256 + threadIdx.x;   // idx = c*K + k  (writes coalesced)
    if (idx < K * C) {
        int c = idx / K;
        int k = idx - c * K;
        WT[idx] = W[(size_t)k * C + c];
    }
}

// ---------------------------------------------------------------------------
// Persistent GRU kernel. Grid = 256 blocks x 256 threads.
// Block bx owns hidden columns [4*bx, 4*bx+4). Thread t: b = t>>2, jj = t&3.
// Each thread computes h'[b, j] per step: 3 gi dots (K=512) + 3 gh dots
// (K=1024) + gate math. One grid.sync() per step (double-buffered h).
// ---------------------------------------------------------------------------
__global__ void __launch_bounds__(256, 1) gru_seq(
    const int*   __restrict__ text,   // [SEQ, BATCH]
    const float* __restrict__ emb,    // [VOCAB, EMBD]
    const float* __restrict__ b_ih,   // [3072]
    const float* __restrict__ b_hh,   // [3072]
    const float* __restrict__ fc_W,   // [HID, NOUT]
    const float* __restrict__ fc_b,   // [NOUT]
    const float* __restrict__ WihT,   // [3072][512]
    const float* __restrict__ WhhT,   // [3072][1024]
    float* __restrict__ h0,
    float* __restrict__ h1,
    float* __restrict__ out)          // [BATCH, NOUT]
{
    cg::grid_group grid = cg::this_grid();

    const int tid = threadIdx.x;
    const int b   = tid >> 2;
    const int jj  = tid & 3;
    const int j   = (blockIdx.x << 2) | jj;

    // Weight rows (transposed layout: contiguous along K)
    const float* wr = WhhT + (size_t)(0 * HID + j) * HID;
    const float* wz = WhhT + (size_t)(1 * HID + j) * HID;
    const float* wn = WhhT + (size_t)(2 * HID + j) * HID;
    const float* ur = WihT + (size_t)(0 * HID + j) * EMBD;
    const float* uz = WihT + (size_t)(1 * HID + j) * EMBD;
    const float* un = WihT + (size_t)(2 * HID + j) * EMBD;

    const float bir  = b_ih[j],           bhr = b_hh[j];
    const float biz  = b_ih[HID + j],     bhz = b_hh[HID + j];
    const float bin_ = b_ih[2 * HID + j], bhn = b_hh[2 * HID + j];

    // h0 := 0 (each block zeroes exactly its own slice)
    h0[b * HID + j] = 0.0f;
    grid.sync();

    for (int t = 0; t < SEQ; ++t) {
        const float* hr = (t & 1) ? h1 : h0;
        float*       hw = (t & 1) ? h0 : h1;

        // ---- gi = x_t @ W_ih + b_ih (columns j, H+j, 2H+j) ----
        const int    row = text[t * BATCH + b];
        const float* x   = emb + (size_t)row * EMBD;
        float air = bir, aiz = biz, ain = bin_;
        #pragma unroll 4
        for (int k = 0; k < EMBD; k += 4) {
            const float4 xv = *(const float4*)(x + k);
            const float4 r4 = *(const float4*)(ur + k);
            const float4 z4 = *(const float4*)(uz + k);
            const float4 n4 = *(const float4*)(un + k);
            air += xv.x * r4.x + xv.y * r4.y + xv.z * r4.z + xv.w * r4.w;
            aiz += xv.x * z4.x + xv.y * z4.y + xv.z * z4.z + xv.w * z4.w;
            ain += xv.x * n4.x + xv.y * n4.y + xv.z * n4.z + xv.w * n4.w;
        }

        // ---- gh = h @ W_hh + b_hh ----
        const float* hb = hr + b * HID;
        float ahr = bhr, ahz = bhz, ahn = bhn;
        #pragma unroll 4
        for (int k = 0; k < HID; k += 4) {
            const float4 hv = *(const float4*)(hb + k);
            const float4 r4 = *(const float4*)(wr + k);
            const float4 z4 = *(const float4*)(wz + k);
            const float4 n4 = *(const float4*)(wn + k);
            ahr += hv.x * r4.x + hv.y * r4.y + hv.z * r4.z + hv.w * r4.w;
            ahz += hv.x * z4.x + hv.y * z4.y + hv.z * z4.z + hv.w * z4.w;
            ahn += hv.x * n4.x + hv.y * n4.y + hv.z * n4.z + hv.w * n4.w;
        }

        // ---- gates ----
        const float r     = 1.0f / (1.0f + __expf(-(air + ahr)));
        const float z     = 1.0f / (1.0f + __expf(-(aiz + ahz)));
        const float n     = tanhf(ain + r * ahn);
        const float hprev = hb[j];
        hw[b * HID + j]   = (1.0f - z) * n + z * hprev;

        grid.sync();   // writes to hw visible before anyone reads it next step
    }

    // ---- final FC: h_final (in h0 after 512 steps) @ fc_W + fc_b ----
    if (blockIdx.x == 0) {
        for (int idx = tid; idx < BATCH * NOUT; idx += 256) {
            const int bb = idx / NOUT;
            const int o  = idx - bb * NOUT;
            float acc = fc_b[o];
            const float* hf = h0 + bb * HID;
            for (int k = 0; k < HID; ++k)
                acc += hf[k] * fc_W[k * NOUT + o];
            out[idx] = acc;
        }
    }
}

// ---------------------------------------------------------------------------
extern "C" void kernel_launch(void* const* d_in, const int* in_sizes, int n_in,
                              void* d_out, int out_size, void* d_ws, size_t ws_size,
                              hipStream_t stream) {
    const int*   text = (const int*)  d_in[0];
    const float* emb  = (const float*)d_in[1];
    const float* W_ih = (const float*)d_in[2];
    const float* W_hh = (const float*)d_in[3];
    const float* b_ih = (const float*)d_in[4];
    const float* b_hh = (const float*)d_in[5];
    const float* fc_W = (const float*)d_in[6];
    const float* fc_b = (const float*)d_in[7];
    float* out = (float*)d_out;

    // ws layout (floats): h0 | h1 | WihT [3072*512] | WhhT [3072*1024]
    // total = 131072 + 1572864 + 3145728 floats ~= 18.5 MB
    float* ws   = (float*)d_ws;
    float* h0   = ws;
    float* h1   = ws + (size_t)BATCH * HID;
    float* WihT = ws + (size_t)2 * BATCH * HID;
    float* WhhT = WihT + (size_t)G3 * EMBD;

    transpose_w<<<(G3 * EMBD + 255) / 256, 256, 0, stream>>>(W_ih, WihT, EMBD, G3);
    transpose_w<<<(G3 * HID  + 255) / 256, 256, 0, stream>>>(W_hh, WhhT, HID,  G3);

    void* args[] = { (void*)&text, (void*)&emb, (void*)&b_ih, (void*)&b_hh,
                     (void*)&fc_W, (void*)&fc_b, (void*)&WihT, (void*)&WhhT,
                     (void*)&h0, (void*)&h1, (void*)&out };
    hipLaunchCooperativeKernel((void*)gru_seq, dim3(256), dim3(256), args, 0, stream);
}

// Round 2
// 13324.068 us; speedup vs baseline: 6.5339x; 6.5339x over previous
//
#include <hip/hip_runtime.h>
#include <hip/hip_cooperative_groups.h>
#include <hip/hip_bf16.h>
#include <math.h>

namespace cg = cooperative_groups;

constexpr int EMBD  = 512;
constexpr int HID   = 1024;
constexpr int NOUT  = 5;
constexpr int SEQ   = 512;
constexpr int BATCH = 64;

constexpr int NBLK = 64;    // cooperative blocks; block owns 16 hidden cols
constexpr int NTHR = 512;   // 8 waves: (mp in 0..1) x (kq in 0..3)
constexpr int JPB  = 16;    // hidden cols per block

typedef __attribute__((ext_vector_type(8))) short bf16x8;
typedef __attribute__((ext_vector_type(4))) float f32x4;

__device__ inline unsigned short f2bf(float f) {
    __hip_bfloat16 h = __float2bfloat16(f);
    return *reinterpret_cast<unsigned short*>(&h);
}

__device__ inline bf16x8 cvt8v(f32x4 a, f32x4 b) {
    bf16x8 r;
#pragma unroll
    for (int i = 0; i < 4; i++) { __hip_bfloat16 h = __float2bfloat16(a[i]); r[i]     = *reinterpret_cast<short*>(&h); }
#pragma unroll
    for (int i = 0; i < 4; i++) { __hip_bfloat16 h = __float2bfloat16(b[i]); r[4 + i] = *reinterpret_cast<short*>(&h); }
    return r;
}

// ---------------------------------------------------------------------------
// Pack W [K, 3072] fp32 -> bf16 MFMA B-fragments, layout [g][nt][kt][lane][8]:
//   k   = kt*32 + (lane>>4)*8 + i
//   col = nt*HID + g*JPB + (lane&15)
// One thread per (g,nt,kt,lane): 8 strided reads, one 16B coalesced write.
// ---------------------------------------------------------------------------
__global__ __launch_bounds__(256) void pack_w(const float* __restrict__ W,
                                              unsigned short* __restrict__ out,
                                              int K) {
    const int nkt = K / 32;
    long idx = (long)blockIdx.x * 256 + threadIdx.x;
    const long total = (long)NBLK * 3 * nkt * 64;
    if (idx >= total) return;
    const int lane = idx & 63;
    long rest = idx >> 6;
    const int kt = rest % nkt; rest /= nkt;
    const int nt = rest % 3;
    const int g  = rest / 3;
    const int k0  = kt * 32 + (lane >> 4) * 8;
    const int col = nt * HID + g * JPB + (lane & 15);
    unsigned short* o = out + idx * 8;
#pragma unroll
    for (int i = 0; i < 8; i++)
        o[i] = f2bf(W[(long)(k0 + i) * 3072 + col]);
}

// ---------------------------------------------------------------------------
// Persistent GRU: 64 blocks x 512 threads, 1 grid.sync per step.
// Wave w = (mp = w>>2, kq = w&3): owns m-tiles {2mp, 2mp+1}, K-quarter kq.
// B-frags streamed from packed global (L2-resident). A (h) read bf16 from the
// broadcast buffer directly into fragment regs. h carry kept fp32 in the
// D-owning lanes (kq==0 waves). x_{t+1} gathered/prefetched during step t.
// ---------------------------------------------------------------------------
__global__ void __launch_bounds__(NTHR, 2) gru_mfma(
    const int*            __restrict__ text,   // [SEQ][BATCH]
    const float*          __restrict__ emb,    // [VOCAB][EMBD]
    const float*          __restrict__ b_ih,   // [3072]
    const float*          __restrict__ b_hh,   // [3072]
    const float*          __restrict__ fc_W,   // [HID][NOUT]
    const float*          __restrict__ fc_b,   // [NOUT]
    const unsigned short* __restrict__ whh_f,  // [64][3][32][64][8]
    const unsigned short* __restrict__ wih_f,  // [64][3][16][64][8]
    unsigned short*       __restrict__ hbuf,   // [2][BATCH][HID] bf16
    float*                __restrict__ hfin,   // [BATCH][HID]
    float*                __restrict__ out)    // [BATCH][NOUT]
{
    cg::grid_group grid = cg::this_grid();
    const int g    = blockIdx.x;
    const int tid  = threadIdx.x;
    const int lane = tid & 63;
    const int w    = tid >> 6;
    const int mp   = w >> 2;   // 0..1
    const int kq   = w & 3;    // 0..3
    const int l16  = lane & 15;
    const int lhi  = lane >> 4;

    __shared__ float red[6][8][256];   // [src wave][tile][lane*4+r] = 48 KB

    const int rowA0 = (mp * 2 + 0) * 16 + l16;   // A-frag rows (b indices)
    const int rowA1 = (mp * 2 + 1) * 16 + l16;

    // zero h buffer 0 (this block's 16-col slice, all b)
    for (int i = tid; i < BATCH * JPB; i += NTHR) {
        const int b = i >> 4, jl = i & 15;
        hbuf[(long)b * HID + g * JPB + jl] = 0;
    }

    // biases for this lane's j (used by kq==0 waves)
    const int jg = g * JPB + l16;
    const float bir  = b_ih[jg],           bhr = b_hh[jg];
    const float biz  = b_ih[HID + jg],     bhz = b_hh[HID + jg];
    const float bin_ = b_ih[2 * HID + jg], bhn = b_hh[2 * HID + jg];

    float hp[2][4] = {{0.f,0.f,0.f,0.f},{0.f,0.f,0.f,0.f}};  // fp32 carry

    bf16x8 xa0[4], xa1[4], xb0[4], xb1[4];

    auto gatherX = [&](int t, bf16x8 (&d0)[4], bf16x8 (&d1)[4]) {
        const int r0 = text[t * BATCH + rowA0];
        const int r1 = text[t * BATCH + rowA1];
        const float* e0 = emb + (long)r0 * EMBD + lhi * 8;
        const float* e1 = emb + (long)r1 * EMBD + lhi * 8;
#pragma unroll
        for (int kk = 0; kk < 4; kk++) {
            const int k0 = (kq * 4 + kk) * 32;
            d0[kk] = cvt8v(*(const f32x4*)(e0 + k0), *(const f32x4*)(e0 + k0 + 4));
            d1[kk] = cvt8v(*(const f32x4*)(e1 + k0), *(const f32x4*)(e1 + k0 + 4));
        }
    };

    gatherX(0, xa0, xa1);

    const unsigned short* whh_g = whh_f + (long)g * 3 * 32 * 64 * 8;
    const unsigned short* wih_g = wih_f + (long)g * 3 * 16 * 64 * 8;

    grid.sync();   // h0 zeroed everywhere

    for (int t = 0; t < SEQ; ++t) {
        const unsigned short* hr = hbuf + (long)(t & 1) * BATCH * HID;
        unsigned short*       hw = hbuf + (long)((t + 1) & 1) * BATCH * HID;

        f32x4 aR0 = {0,0,0,0}, aR1 = {0,0,0,0};
        f32x4 aZ0 = {0,0,0,0}, aZ1 = {0,0,0,0};
        f32x4 aGh0 = {0,0,0,0}, aGh1 = {0,0,0,0};
        f32x4 aGi0 = {0,0,0,0}, aGi1 = {0,0,0,0};

        // prefetch x for next step (off critical path)
        const int tn = (t + 1 < SEQ) ? t + 1 : SEQ - 1;
        gatherX(tn, xb0, xb1);

        // ---- gi: x_t @ W_ih (this wave's K-quarter: 4 ktiles) ----
#pragma unroll
        for (int kk = 0; kk < 4; kk++) {
            const unsigned short* bp = wih_g + (((long)(kq * 4 + kk)) * 64 + lane) * 8;
            const bf16x8 bR = *(const bf16x8*)(bp);
            const bf16x8 bZ = *(const bf16x8*)(bp + 16 * 64 * 8);
            const bf16x8 bN = *(const bf16x8*)(bp + 2 * 16 * 64 * 8);
            aR0  = __builtin_amdgcn_mfma_f32_16x16x32_bf16(xa0[kk], bR, aR0, 0, 0, 0);
            aR1  = __builtin_amdgcn_mfma_f32_16x16x32_bf16(xa1[kk], bR, aR1, 0, 0, 0);
            aZ0  = __builtin_amdgcn_mfma_f32_16x16x32_bf16(xa0[kk], bZ, aZ0, 0, 0, 0);
            aZ1  = __builtin_amdgcn_mfma_f32_16x16x32_bf16(xa1[kk], bZ, aZ1, 0, 0, 0);
            aGi0 = __builtin_amdgcn_mfma_f32_16x16x32_bf16(xa0[kk], bN, aGi0, 0, 0, 0);
            aGi1 = __builtin_amdgcn_mfma_f32_16x16x32_bf16(xa1[kk], bN, aGi1, 0, 0, 0);
        }

        // ---- gh: h_t @ W_hh (this wave's K-quarter: 8 ktiles) ----
#pragma unroll
        for (int kk = 0; kk < 8; kk++) {
            const int kt = kq * 8 + kk;
            const int k0 = kt * 32 + lhi * 8;
            const bf16x8 ha0 = *(const bf16x8*)(hr + (long)rowA0 * HID + k0);
            const bf16x8 ha1 = *(const bf16x8*)(hr + (long)rowA1 * HID + k0);
            const unsigned short* bp = whh_g + (((long)kt) * 64 + lane) * 8;
            const bf16x8 bR = *(const bf16x8*)(bp);
            const bf16x8 bZ = *(const bf16x8*)(bp + 32 * 64 * 8);
            const bf16x8 bN = *(const bf16x8*)(bp + 2 * 32 * 64 * 8);
            aR0  = __builtin_amdgcn_mfma_f32_16x16x32_bf16(ha0, bR, aR0, 0, 0, 0);
            aR1  = __builtin_amdgcn_mfma_f32_16x16x32_bf16(ha1, bR, aR1, 0, 0, 0);
            aZ0  = __builtin_amdgcn_mfma_f32_16x16x32_bf16(ha0, bZ, aZ0, 0, 0, 0);
            aZ1  = __builtin_amdgcn_mfma_f32_16x16x32_bf16(ha1, bZ, aZ1, 0, 0, 0);
            aGh0 = __builtin_amdgcn_mfma_f32_16x16x32_bf16(ha0, bN, aGh0, 0, 0, 0);
            aGh1 = __builtin_amdgcn_mfma_f32_16x16x32_bf16(ha1, bN, aGh1, 0, 0, 0);
        }

        // ---- K-quarter reduction via LDS ----
        if (kq != 0) {
            const int s = mp * 3 + (kq - 1);
            *(f32x4*)&red[s][0][lane * 4] = aR0;
            *(f32x4*)&red[s][1][lane * 4] = aR1;
            *(f32x4*)&red[s][2][lane * 4] = aZ0;
            *(f32x4*)&red[s][3][lane * 4] = aZ1;
            *(f32x4*)&red[s][4][lane * 4] = aGh0;
            *(f32x4*)&red[s][5][lane * 4] = aGh1;
            *(f32x4*)&red[s][6][lane * 4] = aGi0;
            *(f32x4*)&red[s][7][lane * 4] = aGi1;
        }
        __syncthreads();
        if (kq == 0) {
#pragma unroll
            for (int p = 0; p < 3; p++) {
                const int s = mp * 3 + p;
                aR0  += *(const f32x4*)&red[s][0][lane * 4];
                aR1  += *(const f32x4*)&red[s][1][lane * 4];
                aZ0  += *(const f32x4*)&red[s][2][lane * 4];
                aZ1  += *(const f32x4*)&red[s][3][lane * 4];
                aGh0 += *(const f32x4*)&red[s][4][lane * 4];
                aGh1 += *(const f32x4*)&red[s][5][lane * 4];
                aGi0 += *(const f32x4*)&red[s][6][lane * 4];
                aGi1 += *(const f32x4*)&red[s][7][lane * 4];
            }
            // ---- gate math: D-frag (b,j) is lane-local; fp32 carry ----
#pragma unroll
            for (int m = 0; m < 2; m++) {
                const f32x4 R  = m ? aR1  : aR0;
                const f32x4 Z  = m ? aZ1  : aZ0;
                const f32x4 Gh = m ? aGh1 : aGh0;
                const f32x4 Gi = m ? aGi1 : aGi0;
#pragma unroll
                for (int r = 0; r < 4; r++) {
                    const float rr = 1.f / (1.f + __expf(-(R[r] + bir + bhr)));
                    const float zz = 1.f / (1.f + __expf(-(Z[r] + biz + bhz)));
                    const float nn = tanhf(Gi[r] + bin_ + rr * (Gh[r] + bhn));
                    const float hn = (1.f - zz) * nn + zz * hp[m][r];
                    hp[m][r] = hn;
                    const int b = (mp * 2 + m) * 16 + lhi * 4 + r;
                    hw[(long)b * HID + jg] = f2bf(hn);
                }
            }
        }
#pragma unroll
        for (int kk = 0; kk < 4; kk++) { xa0[kk] = xb0[kk]; xa1[kk] = xb1[kk]; }
        grid.sync();
    }

    // ---- epilogue: write fp32 h_final, then block 0 does the tiny FC ----
    if (kq == 0) {
#pragma unroll
        for (int m = 0; m < 2; m++)
#pragma unroll
            for (int r = 0; r < 4; r++) {
                const int b = (mp * 2 + m) * 16 + lhi * 4 + r;
                hfin[(long)b * HID + jg] = hp[m][r];
            }
    }
    grid.sync();
    if (g == 0) {
        for (int i = tid; i < BATCH * NOUT; i += NTHR) {
            const int b = i / NOUT, o = i - b * NOUT;
            float acc = fc_b[o];
            const float* hf = hfin + (long)b * HID;
            for (int k = 0; k < HID; k += 4) {
                acc += hf[k]     * fc_W[(k)     * NOUT + o];
                acc += hf[k + 1] * fc_W[(k + 1) * NOUT + o];
                acc += hf[k + 2] * fc_W[(k + 2) * NOUT + o];
                acc += hf[k + 3] * fc_W[(k + 3) * NOUT + o];
            }
            out[i] = acc;
        }
    }
}

// ---------------------------------------------------------------------------
extern "C" void kernel_launch(void* const* d_in, const int* in_sizes, int n_in,
                              void* d_out, int out_size, void* d_ws, size_t ws_size,
                              hipStream_t stream) {
    const int*   text = (const int*)  d_in[0];
    const float* emb  = (const float*)d_in[1];
    const float* W_ih = (const float*)d_in[2];
    const float* W_hh = (const float*)d_in[3];
    const float* b_ih = (const float*)d_in[4];
    const float* b_hh = (const float*)d_in[5];
    const float* fc_W = (const float*)d_in[6];
    const float* fc_b = (const float*)d_in[7];
    float* out = (float*)d_out;

    // ws layout (bytes):
    //   hbuf  [2][64][1024] bf16   : 262144
    //   hfin  [64][1024] f32       : 262144
    //   whh_f [64][3][32][64][8]   : 6291456
    //   wih_f [64][3][16][64][8]   : 3145728
    char* ws = (char*)d_ws;
    unsigned short* hbuf  = (unsigned short*)(ws);
    float*          hfin  = (float*)(ws + 262144);
    unsigned short* whh_f = (unsigned short*)(ws + 262144 + 262144);
    unsigned short* wih_f = (unsigned short*)(ws + 262144 + 262144 + 6291456);

    const long nfrag_hh = (long)NBLK * 3 * 32 * 64;   // 393216
    const long nfrag_ih = (long)NBLK * 3 * 16 * 64;   // 196608
    pack_w<<<(int)((nfrag_hh + 255) / 256), 256, 0, stream>>>(W_hh, whh_f, HID);
    pack_w<<<(int)((nfrag_ih + 255) / 256), 256, 0, stream>>>(W_ih, wih_f, EMBD);

    void* args[] = { (void*)&text, (void*)&emb, (void*)&b_ih, (void*)&b_hh,
                     (void*)&fc_W, (void*)&fc_b, (void*)&whh_f, (void*)&wih_f,
                     (void*)&hbuf, (void*)&hfin, (void*)&out };
    hipLaunchCooperativeKernel((void*)gru_mfma, dim3(NBLK), dim3(NTHR), args, 0, stream);
}

// Round 3
// 11127.093 us; speedup vs baseline: 7.8239x; 1.1974x over previous
//
#include <hip/hip_runtime.h>
#include <hip/hip_cooperative_groups.h>
#include <hip/hip_bf16.h>
#include <math.h>

constexpr int EMBD  = 512;
constexpr int HID   = 1024;
constexpr int NOUT  = 5;
constexpr int SEQ   = 512;
constexpr int BATCH = 64;

constexpr int NBLK = 64;    // cooperative blocks; block owns 16 hidden cols
constexpr int NTHR = 512;   // 8 waves: (mp in 0..1) x (kq in 0..3)
constexpr int JPB  = 16;    // hidden cols per block

typedef __attribute__((ext_vector_type(8))) short bf16x8;
typedef __attribute__((ext_vector_type(4))) float f32x4;

__device__ inline unsigned short f2bf(float f) {
    __hip_bfloat16 h = __float2bfloat16(f);
    return *reinterpret_cast<unsigned short*>(&h);
}

__device__ inline bf16x8 cvt8v(f32x4 a, f32x4 b) {
    bf16x8 r;
#pragma unroll
    for (int i = 0; i < 4; i++) { __hip_bfloat16 h = __float2bfloat16(a[i]); r[i]     = *reinterpret_cast<short*>(&h); }
#pragma unroll
    for (int i = 0; i < 4; i++) { __hip_bfloat16 h = __float2bfloat16(b[i]); r[4 + i] = *reinterpret_cast<short*>(&h); }
    return r;
}

// Agent-scope (LLC-coherent) h exchange: bypasses possibly-stale L1/L2 lines
// (emits global_load/store ... sc0 sc1). No fences -> no L2 invalidation.
__device__ inline bf16x8 load_h16(const unsigned short* p) {
    unsigned long long lo = __hip_atomic_load((const unsigned long long*)p,
                              __ATOMIC_RELAXED, __HIP_MEMORY_SCOPE_AGENT);
    unsigned long long hi = __hip_atomic_load(((const unsigned long long*)p) + 1,
                              __ATOMIC_RELAXED, __HIP_MEMORY_SCOPE_AGENT);
    union { unsigned long long u[2]; bf16x8 v; } r;
    r.u[0] = lo; r.u[1] = hi;
    return r.v;
}

__device__ inline void store_h(unsigned short* p, unsigned short v) {
    __hip_atomic_store(p, v, __ATOMIC_RELAXED, __HIP_MEMORY_SCOPE_AGENT);
}

// Flush-free grid barrier: fresh counter per step (no sense reversal / reset
// races). Relaxed agent atomics only -> no buffer_inv / buffer_wbl2.
// Data ordering: each wave drains vmcnt(0) before the block's __syncthreads;
// h data moved with sc0|sc1 ops is at the LLC once acked, so flag-after-data
// is sufficient for cross-XCD visibility.
__device__ inline void grid_barrier(int* cnt, int idx) {
    __syncthreads();
    if (threadIdx.x == 0) {
        __hip_atomic_fetch_add(&cnt[idx], 1, __ATOMIC_RELAXED, __HIP_MEMORY_SCOPE_AGENT);
        while (__hip_atomic_load(&cnt[idx], __ATOMIC_RELAXED, __HIP_MEMORY_SCOPE_AGENT) < NBLK)
            __builtin_amdgcn_s_sleep(1);
    }
    __syncthreads();
}

// ---------------------------------------------------------------------------
// Pack W [K, 3072] fp32 -> bf16 MFMA B-fragments, layout [g][nt][kt][lane][8]:
//   k   = kt*32 + (lane>>4)*8 + i
//   col = nt*HID + g*JPB + (lane&15)
// ---------------------------------------------------------------------------
__global__ __launch_bounds__(256) void pack_w(const float* __restrict__ W,
                                              unsigned short* __restrict__ out,
                                              int K) {
    const int nkt = K / 32;
    long idx = (long)blockIdx.x * 256 + threadIdx.x;
    const long total = (long)NBLK * 3 * nkt * 64;
    if (idx >= total) return;
    const int lane = idx & 63;
    long rest = idx >> 6;
    const int kt = rest % nkt; rest /= nkt;
    const int nt = rest % 3;
    const int g  = rest / 3;
    const int k0  = kt * 32 + (lane >> 4) * 8;
    const int col = nt * HID + g * JPB + (lane & 15);
    unsigned short* o = out + idx * 8;
#pragma unroll
    for (int i = 0; i < 8; i++)
        o[i] = f2bf(W[(long)(k0 + i) * 3072 + col]);
}

// ---------------------------------------------------------------------------
// Persistent GRU: 64 blocks x 512 threads, 1 flush-free barrier per step.
// Wave w = (mp = w>>2, kq = w&3): owns m-tiles {2mp, 2mp+1}, K-quarter kq.
// Weights stream from L2 (never invalidated now). h exchanged via LLC.
// ---------------------------------------------------------------------------
__global__ void __launch_bounds__(NTHR, 2) gru_mfma(
    const int*            __restrict__ text,   // [SEQ][BATCH]
    const float*          __restrict__ emb,    // [VOCAB][EMBD]
    const float*          __restrict__ b_ih,   // [3072]
    const float*          __restrict__ b_hh,   // [3072]
    const float*          __restrict__ fc_W,   // [HID][NOUT]
    const float*          __restrict__ fc_b,   // [NOUT]
    const unsigned short* __restrict__ whh_f,  // [64][3][32][64][8]
    const unsigned short* __restrict__ wih_f,  // [64][3][16][64][8]
    unsigned short*       __restrict__ hbuf,   // [2][BATCH][HID] bf16
    int*                  __restrict__ cnt,    // [SEQ+1] barrier counters (zeroed)
    float*                __restrict__ out)    // [BATCH][NOUT] (zeroed)
{
    const int g    = blockIdx.x;
    const int tid  = threadIdx.x;
    const int lane = tid & 63;
    const int w    = tid >> 6;
    const int mp   = w >> 2;   // 0..1
    const int kq   = w & 3;    // 0..3
    const int l16  = lane & 15;
    const int lhi  = lane >> 4;

    __shared__ float red[6][8][256];   // [src wave][tile][lane*4+r] = 48 KB

    const int rowA0 = (mp * 2 + 0) * 16 + l16;   // A-frag rows (b indices)
    const int rowA1 = (mp * 2 + 1) * 16 + l16;

    // zero h buffer 0 (this block's 16-col slice, all b) via LLC stores
    for (int i = tid; i < BATCH * JPB; i += NTHR) {
        const int b = i >> 4, jl = i & 15;
        store_h(&hbuf[(long)b * HID + g * JPB + jl], 0);
    }
    asm volatile("s_waitcnt vmcnt(0)" ::: "memory");

    // biases for this lane's j (used by kq==0 waves)
    const int jg = g * JPB + l16;
    const float bir  = b_ih[jg],           bhr = b_hh[jg];
    const float biz  = b_ih[HID + jg],     bhz = b_hh[HID + jg];
    const float bin_ = b_ih[2 * HID + jg], bhn = b_hh[2 * HID + jg];

    float hp[2][4] = {{0.f,0.f,0.f,0.f},{0.f,0.f,0.f,0.f}};  // fp32 carry

    bf16x8 xa0[4], xa1[4], xb0[4], xb1[4];

    auto gatherX = [&](int t, bf16x8 (&d0)[4], bf16x8 (&d1)[4]) {
        const int r0 = text[t * BATCH + rowA0];
        const int r1 = text[t * BATCH + rowA1];
        const float* e0 = emb + (long)r0 * EMBD + lhi * 8;
        const float* e1 = emb + (long)r1 * EMBD + lhi * 8;
#pragma unroll
        for (int kk = 0; kk < 4; kk++) {
            const int k0 = (kq * 4 + kk) * 32;
            d0[kk] = cvt8v(*(const f32x4*)(e0 + k0), *(const f32x4*)(e0 + k0 + 4));
            d1[kk] = cvt8v(*(const f32x4*)(e1 + k0), *(const f32x4*)(e1 + k0 + 4));
        }
    };

    gatherX(0, xa0, xa1);

    const unsigned short* whh_g = whh_f + (long)g * 3 * 32 * 64 * 8;
    const unsigned short* wih_g = wih_f + (long)g * 3 * 16 * 64 * 8;

    grid_barrier(cnt, 0);   // h0 zeroed everywhere

    for (int t = 0; t < SEQ; ++t) {
        const unsigned short* hr = hbuf + (long)(t & 1) * BATCH * HID;
        unsigned short*       hw = hbuf + (long)((t + 1) & 1) * BATCH * HID;

        // ---- issue ALL h-fragment loads first (LLC latency hides under gi) ----
        bf16x8 ha0[8], ha1[8];
#pragma unroll
        for (int kk = 0; kk < 8; kk++) {
            const int k0 = (kq * 8 + kk) * 32 + lhi * 8;
            ha0[kk] = load_h16(hr + (long)rowA0 * HID + k0);
            ha1[kk] = load_h16(hr + (long)rowA1 * HID + k0);
        }

        f32x4 aR0 = {0,0,0,0}, aR1 = {0,0,0,0};
        f32x4 aZ0 = {0,0,0,0}, aZ1 = {0,0,0,0};
        f32x4 aGh0 = {0,0,0,0}, aGh1 = {0,0,0,0};
        f32x4 aGi0 = {0,0,0,0}, aGi1 = {0,0,0,0};

        // prefetch x for next step (off critical path, cached loads)
        const int tn = (t + 1 < SEQ) ? t + 1 : SEQ - 1;
        gatherX(tn, xb0, xb1);

        // ---- gi: x_t @ W_ih (this wave's K-quarter: 4 ktiles) ----
#pragma unroll
        for (int kk = 0; kk < 4; kk++) {
            const unsigned short* bp = wih_g + (((long)(kq * 4 + kk)) * 64 + lane) * 8;
            const bf16x8 bR = *(const bf16x8*)(bp);
            const bf16x8 bZ = *(const bf16x8*)(bp + 16 * 64 * 8);
            const bf16x8 bN = *(const bf16x8*)(bp + 2 * 16 * 64 * 8);
            aR0  = __builtin_amdgcn_mfma_f32_16x16x32_bf16(xa0[kk], bR, aR0, 0, 0, 0);
            aR1  = __builtin_amdgcn_mfma_f32_16x16x32_bf16(xa1[kk], bR, aR1, 0, 0, 0);
            aZ0  = __builtin_amdgcn_mfma_f32_16x16x32_bf16(xa0[kk], bZ, aZ0, 0, 0, 0);
            aZ1  = __builtin_amdgcn_mfma_f32_16x16x32_bf16(xa1[kk], bZ, aZ1, 0, 0, 0);
            aGi0 = __builtin_amdgcn_mfma_f32_16x16x32_bf16(xa0[kk], bN, aGi0, 0, 0, 0);
            aGi1 = __builtin_amdgcn_mfma_f32_16x16x32_bf16(xa1[kk], bN, aGi1, 0, 0, 0);
        }

        // ---- gh: h_t @ W_hh (this wave's K-quarter: 8 ktiles) ----
#pragma unroll
        for (int kk = 0; kk < 8; kk++) {
            const int kt = kq * 8 + kk;
            const unsigned short* bp = whh_g + (((long)kt) * 64 + lane) * 8;
            const bf16x8 bR = *(const bf16x8*)(bp);
            const bf16x8 bZ = *(const bf16x8*)(bp + 32 * 64 * 8);
            const bf16x8 bN = *(const bf16x8*)(bp + 2 * 32 * 64 * 8);
            aR0  = __builtin_amdgcn_mfma_f32_16x16x32_bf16(ha0[kk], bR, aR0, 0, 0, 0);
            aR1  = __builtin_amdgcn_mfma_f32_16x16x32_bf16(ha1[kk], bR, aR1, 0, 0, 0);
            aZ0  = __builtin_amdgcn_mfma_f32_16x16x32_bf16(ha0[kk], bZ, aZ0, 0, 0, 0);
            aZ1  = __builtin_amdgcn_mfma_f32_16x16x32_bf16(ha1[kk], bZ, aZ1, 0, 0, 0);
            aGh0 = __builtin_amdgcn_mfma_f32_16x16x32_bf16(ha0[kk], bN, aGh0, 0, 0, 0);
            aGh1 = __builtin_amdgcn_mfma_f32_16x16x32_bf16(ha1[kk], bN, aGh1, 0, 0, 0);
        }

        // ---- K-quarter reduction via LDS ----
        if (kq != 0) {
            const int s = mp * 3 + (kq - 1);
            *(f32x4*)&red[s][0][lane * 4] = aR0;
            *(f32x4*)&red[s][1][lane * 4] = aR1;
            *(f32x4*)&red[s][2][lane * 4] = aZ0;
            *(f32x4*)&red[s][3][lane * 4] = aZ1;
            *(f32x4*)&red[s][4][lane * 4] = aGh0;
            *(f32x4*)&red[s][5][lane * 4] = aGh1;
            *(f32x4*)&red[s][6][lane * 4] = aGi0;
            *(f32x4*)&red[s][7][lane * 4] = aGi1;
        }
        __syncthreads();
        if (kq == 0) {
#pragma unroll
            for (int p = 0; p < 3; p++) {
                const int s = mp * 3 + p;
                aR0  += *(const f32x4*)&red[s][0][lane * 4];
                aR1  += *(const f32x4*)&red[s][1][lane * 4];
                aZ0  += *(const f32x4*)&red[s][2][lane * 4];
                aZ1  += *(const f32x4*)&red[s][3][lane * 4];
                aGh0 += *(const f32x4*)&red[s][4][lane * 4];
                aGh1 += *(const f32x4*)&red[s][5][lane * 4];
                aGi0 += *(const f32x4*)&red[s][6][lane * 4];
                aGi1 += *(const f32x4*)&red[s][7][lane * 4];
            }
            // ---- gate math: D-frag (b,j) lane-local; fp32 carry ----
#pragma unroll
            for (int m = 0; m < 2; m++) {
                const f32x4 R  = m ? aR1  : aR0;
                const f32x4 Z  = m ? aZ1  : aZ0;
                const f32x4 Gh = m ? aGh1 : aGh0;
                const f32x4 Gi = m ? aGi1 : aGi0;
#pragma unroll
                for (int r = 0; r < 4; r++) {
                    const float rr = 1.f / (1.f + __expf(-(R[r] + bir + bhr)));
                    const float zz = 1.f / (1.f + __expf(-(Z[r] + biz + bhz)));
                    const float nn = tanhf(Gi[r] + bin_ + rr * (Gh[r] + bhn));
                    const float hn = (1.f - zz) * nn + zz * hp[m][r];
                    hp[m][r] = hn;
                    const int b = (mp * 2 + m) * 16 + lhi * 4 + r;
                    store_h(&hw[(long)b * HID + jg], f2bf(hn));
                }
            }
            asm volatile("s_waitcnt vmcnt(0)" ::: "memory");  // h at LLC before flag
        }
#pragma unroll
        for (int kk = 0; kk < 4; kk++) { xa0[kk] = xb0[kk]; xa1[kk] = xb1[kk]; }

        grid_barrier(cnt, t + 1);
    }

    // ---- epilogue: block-local FC partial over its 16 cols, atomicAdd out ----
    float (*hsl)[JPB] = reinterpret_cast<float(*)[JPB]>(&red[0][0][0]);  // [64][16]
    if (kq == 0) {
#pragma unroll
        for (int m = 0; m < 2; m++)
#pragma unroll
            for (int r = 0; r < 4; r++) {
                const int b = (mp * 2 + m) * 16 + lhi * 4 + r;
                hsl[b][l16] = hp[m][r];
            }
    }
    __syncthreads();
    if (tid < BATCH * NOUT) {
        const int b = tid / NOUT, o = tid - b * NOUT;
        float acc = (g == 0) ? fc_b[o] : 0.0f;
#pragma unroll
        for (int jl = 0; jl < JPB; jl++)
            acc += hsl[b][jl] * fc_W[(g * JPB + jl) * NOUT + o];
        atomicAdd(&out[tid], acc);
    }
}

// ---------------------------------------------------------------------------
extern "C" void kernel_launch(void* const* d_in, const int* in_sizes, int n_in,
                              void* d_out, int out_size, void* d_ws, size_t ws_size,
                              hipStream_t stream) {
    const int*   text = (const int*)  d_in[0];
    const float* emb  = (const float*)d_in[1];
    const float* W_ih = (const float*)d_in[2];
    const float* W_hh = (const float*)d_in[3];
    const float* b_ih = (const float*)d_in[4];
    const float* b_hh = (const float*)d_in[5];
    const float* fc_W = (const float*)d_in[6];
    const float* fc_b = (const float*)d_in[7];
    float* out = (float*)d_out;

    // ws layout (bytes):
    //   cnt   [SEQ+1] int (rounded to 4096)        : 4096
    //   hbuf  [2][64][1024] bf16                   : 262144
    //   whh_f [64][3][32][64][8] bf16              : 6291456
    //   wih_f [64][3][16][64][8] bf16              : 3145728
    char* ws = (char*)d_ws;
    int*            cnt   = (int*)(ws);
    unsigned short* hbuf  = (unsigned short*)(ws + 4096);
    unsigned short* whh_f = (unsigned short*)(ws + 4096 + 262144);
    unsigned short* wih_f = (unsigned short*)(ws + 4096 + 262144 + 6291456);

    hipMemsetAsync(cnt, 0, 4096, stream);                         // barrier counters
    hipMemsetAsync(out, 0, (size_t)out_size * sizeof(float), stream);  // atomicAdd target

    const long nfrag_hh = (long)NBLK * 3 * 32 * 64;   // 393216
    const long nfrag_ih = (long)NBLK * 3 * 16 * 64;   // 196608
    pack_w<<<(int)((nfrag_hh + 255) / 256), 256, 0, stream>>>(W_hh, whh_f, HID);
    pack_w<<<(int)((nfrag_ih + 255) / 256), 256, 0, stream>>>(W_ih, wih_f, EMBD);

    void* args[] = { (void*)&text, (void*)&emb, (void*)&b_ih, (void*)&b_hh,
                     (void*)&fc_W, (void*)&fc_b, (void*)&whh_f, (void*)&wih_f,
                     (void*)&hbuf, (void*)&cnt, (void*)&out };
    hipLaunchCooperativeKernel((void*)gru_mfma, dim3(NBLK), dim3(NTHR), args, 0, stream);
}

// Round 4
// 8238.731 us; speedup vs baseline: 10.5669x; 1.3506x over previous
//
#include <hip/hip_runtime.h>
#include <hip/hip_cooperative_groups.h>
#include <hip/hip_bf16.h>
#include <math.h>

constexpr int EMBD  = 512;
constexpr int HID   = 1024;
constexpr int NOUT  = 5;
constexpr int SEQ   = 512;
constexpr int BATCH = 64;

constexpr int NBLK = 64;    // cooperative blocks; block owns 16 hidden cols
constexpr int NTHR = 512;   // 8 waves: (mp in 0..1) x (kq in 0..3)
constexpr int JPB  = 16;    // hidden cols per block
constexpr int FPAD = 16;    // flag padding (ints) -> 64 B/flag, own line region

typedef __attribute__((ext_vector_type(8))) short bf16x8;
typedef __attribute__((ext_vector_type(4))) float f32x4;

__device__ inline unsigned short f2bf(float f) {
    __hip_bfloat16 h = __float2bfloat16(f);
    return *reinterpret_cast<unsigned short*>(&h);
}

__device__ inline bf16x8 cvt8v(f32x4 a, f32x4 b) {
    bf16x8 r;
#pragma unroll
    for (int i = 0; i < 4; i++) { __hip_bfloat16 h = __float2bfloat16(a[i]); r[i]     = *reinterpret_cast<short*>(&h); }
#pragma unroll
    for (int i = 0; i < 4; i++) { __hip_bfloat16 h = __float2bfloat16(b[i]); r[4 + i] = *reinterpret_cast<short*>(&h); }
    return r;
}

// Agent-scope (LLC-coherent) h exchange: bypasses possibly-stale L1/L2.
__device__ inline bf16x8 load_h16(const unsigned short* p) {
    unsigned long long lo = __hip_atomic_load((const unsigned long long*)p,
                              __ATOMIC_RELAXED, __HIP_MEMORY_SCOPE_AGENT);
    unsigned long long hi = __hip_atomic_load(((const unsigned long long*)p) + 1,
                              __ATOMIC_RELAXED, __HIP_MEMORY_SCOPE_AGENT);
    union { unsigned long long u[2]; bf16x8 v; } r;
    r.u[0] = lo; r.u[1] = hi;
    return r.v;
}

__device__ inline void store_h(unsigned short* p, unsigned short v) {
    __hip_atomic_store(p, v, __ATOMIC_RELAXED, __HIP_MEMORY_SCOPE_AGENT);
}

// Distributed-flag grid barrier: NO atomic RMW anywhere.
// Arrival: each wave drains its own vmem (h stores acked at LLC), block
// syncs, then one thread STORES flags[g] = ep (private padded slot).
// Detection: wave 0's 64 lanes load all 64 flags in ONE instruction and
// re-poll until all >= ep. Epoch increases monotonically -> no reset/ABA.
__device__ inline void flag_barrier(int* flags, int g, int ep) {
    asm volatile("s_waitcnt vmcnt(0)" ::: "memory");
    __syncthreads();
    if (threadIdx.x == 0)
        __hip_atomic_store(&flags[g * FPAD], ep, __ATOMIC_RELAXED, __HIP_MEMORY_SCOPE_AGENT);
    if (threadIdx.x < 64) {
        int f;
        do {
            f = __hip_atomic_load(&flags[threadIdx.x * FPAD],
                                  __ATOMIC_RELAXED, __HIP_MEMORY_SCOPE_AGENT);
        } while (__any(f < ep));
    }
    __syncthreads();
}

// ---------------------------------------------------------------------------
// Pack W [K, 3072] fp32 -> bf16 MFMA B-fragments, layout [g][nt][kt][lane][8]
// ---------------------------------------------------------------------------
__global__ __launch_bounds__(256) void pack_w(const float* __restrict__ W,
                                              unsigned short* __restrict__ out,
                                              int K) {
    const int nkt = K / 32;
    long idx = (long)blockIdx.x * 256 + threadIdx.x;
    const long total = (long)NBLK * 3 * nkt * 64;
    if (idx >= total) return;
    const int lane = idx & 63;
    long rest = idx >> 6;
    const int kt = rest % nkt; rest /= nkt;
    const int nt = rest % 3;
    const int g  = rest / 3;
    const int k0  = kt * 32 + (lane >> 4) * 8;
    const int col = nt * HID + g * JPB + (lane & 15);
    unsigned short* o = out + idx * 8;
#pragma unroll
    for (int i = 0; i < 8; i++)
        o[i] = f2bf(W[(long)(k0 + i) * 3072 + col]);
}

// ---------------------------------------------------------------------------
// Persistent GRU: 64 blocks x 512 threads, flag barrier per step.
// Wave w = (mp = w>>2, kq = w&3). MFMA phase: wave owns m-tiles {2mp,2mp+1},
// K-quarter kq. Reduce/gate phase: waves with kq<2 each own ONE mtile
// m = mp*2 + kq (reduce partials of their mp-group, gates, carry, store).
// ---------------------------------------------------------------------------
__global__ void __launch_bounds__(NTHR, 2) gru_mfma(
    const int*            __restrict__ text,   // [SEQ][BATCH]
    const float*          __restrict__ emb,    // [VOCAB][EMBD]
    const float*          __restrict__ b_ih,   // [3072]
    const float*          __restrict__ b_hh,   // [3072]
    const float*          __restrict__ fc_W,   // [HID][NOUT]
    const float*          __restrict__ fc_b,   // [NOUT]
    const unsigned short* __restrict__ whh_f,  // [64][3][32][64][8]
    const unsigned short* __restrict__ wih_f,  // [64][3][16][64][8]
    unsigned short*       __restrict__ hbuf,   // [2][BATCH][HID] bf16
    int*                  __restrict__ flags,  // [64*FPAD] (zeroed)
    float*                __restrict__ out)    // [BATCH][NOUT] (zeroed)
{
    const int g    = blockIdx.x;
    const int tid  = threadIdx.x;
    const int lane = tid & 63;
    const int w    = tid >> 6;
    const int mp   = w >> 2;   // 0..1
    const int kq   = w & 3;    // 0..3
    const int l16  = lane & 15;
    const int lhi  = lane >> 4;

    __shared__ float red[8][8][256];   // [wave][tile][lane*4+r] = 64 KB

    const int rowA0 = (mp * 2 + 0) * 16 + l16;   // A-frag rows (b indices)
    const int rowA1 = (mp * 2 + 1) * 16 + l16;

    // zero h buffer 0 (this block's 16-col slice, all b) via LLC stores
    for (int i = tid; i < BATCH * JPB; i += NTHR) {
        const int b = i >> 4, jl = i & 15;
        store_h(&hbuf[(long)b * HID + g * JPB + jl], 0);
    }

    // biases for this lane's j (used by gate waves)
    const int jg = g * JPB + l16;
    const float bir  = b_ih[jg],           bhr = b_hh[jg];
    const float biz  = b_ih[HID + jg],     bhz = b_hh[HID + jg];
    const float bin_ = b_ih[2 * HID + jg], bhn = b_hh[2 * HID + jg];

    const bool gateW = (kq < 2);
    const int  mt    = mp * 2 + kq;          // gate wave's mtile (kq<2 only)
    float hp[4] = {0.f, 0.f, 0.f, 0.f};      // fp32 carry (gate waves)

    bf16x8 xa0[4], xa1[4], xb0[4], xb1[4];

    auto gatherX = [&](int t, bf16x8 (&d0)[4], bf16x8 (&d1)[4]) {
        const int r0 = text[t * BATCH + rowA0];
        const int r1 = text[t * BATCH + rowA1];
        const float* e0 = emb + (long)r0 * EMBD + lhi * 8;
        const float* e1 = emb + (long)r1 * EMBD + lhi * 8;
#pragma unroll
        for (int kk = 0; kk < 4; kk++) {
            const int k0 = (kq * 4 + kk) * 32;
            d0[kk] = cvt8v(*(const f32x4*)(e0 + k0), *(const f32x4*)(e0 + k0 + 4));
            d1[kk] = cvt8v(*(const f32x4*)(e1 + k0), *(const f32x4*)(e1 + k0 + 4));
        }
    };

    gatherX(0, xa0, xa1);

    const unsigned short* whh_g = whh_f + (long)g * 3 * 32 * 64 * 8;
    const unsigned short* wih_g = wih_f + (long)g * 3 * 16 * 64 * 8;

    flag_barrier(flags, g, 1);   // h0 zeroed everywhere

    for (int t = 0; t < SEQ; ++t) {
        const unsigned short* hr = hbuf + (long)(t & 1) * BATCH * HID;
        unsigned short*       hw = hbuf + (long)((t + 1) & 1) * BATCH * HID;

        // ---- issue ALL h-fragment loads first (LLC latency hides under gi) ----
        bf16x8 ha0[8], ha1[8];
#pragma unroll
        for (int kk = 0; kk < 8; kk++) {
            const int k0 = (kq * 8 + kk) * 32 + lhi * 8;
            ha0[kk] = load_h16(hr + (long)rowA0 * HID + k0);
            ha1[kk] = load_h16(hr + (long)rowA1 * HID + k0);
        }

        f32x4 aR0 = {0,0,0,0}, aR1 = {0,0,0,0};
        f32x4 aZ0 = {0,0,0,0}, aZ1 = {0,0,0,0};
        f32x4 aGh0 = {0,0,0,0}, aGh1 = {0,0,0,0};
        f32x4 aGi0 = {0,0,0,0}, aGi1 = {0,0,0,0};

        // prefetch x for next step (off critical path, cached loads)
        const int tn = (t + 1 < SEQ) ? t + 1 : SEQ - 1;
        gatherX(tn, xb0, xb1);

        // ---- gi: x_t @ W_ih (this wave's K-quarter: 4 ktiles) ----
#pragma unroll
        for (int kk = 0; kk < 4; kk++) {
            const unsigned short* bp = wih_g + (((long)(kq * 4 + kk)) * 64 + lane) * 8;
            const bf16x8 bR = *(const bf16x8*)(bp);
            const bf16x8 bZ = *(const bf16x8*)(bp + 16 * 64 * 8);
            const bf16x8 bN = *(const bf16x8*)(bp + 2 * 16 * 64 * 8);
            aR0  = __builtin_amdgcn_mfma_f32_16x16x32_bf16(xa0[kk], bR, aR0, 0, 0, 0);
            aR1  = __builtin_amdgcn_mfma_f32_16x16x32_bf16(xa1[kk], bR, aR1, 0, 0, 0);
            aZ0  = __builtin_amdgcn_mfma_f32_16x16x32_bf16(xa0[kk], bZ, aZ0, 0, 0, 0);
            aZ1  = __builtin_amdgcn_mfma_f32_16x16x32_bf16(xa1[kk], bZ, aZ1, 0, 0, 0);
            aGi0 = __builtin_amdgcn_mfma_f32_16x16x32_bf16(xa0[kk], bN, aGi0, 0, 0, 0);
            aGi1 = __builtin_amdgcn_mfma_f32_16x16x32_bf16(xa1[kk], bN, aGi1, 0, 0, 0);
        }

        // ---- gh: h_t @ W_hh (this wave's K-quarter: 8 ktiles) ----
#pragma unroll
        for (int kk = 0; kk < 8; kk++) {
            const int kt = kq * 8 + kk;
            const unsigned short* bp = whh_g + (((long)kt) * 64 + lane) * 8;
            const bf16x8 bR = *(const bf16x8*)(bp);
            const bf16x8 bZ = *(const bf16x8*)(bp + 32 * 64 * 8);
            const bf16x8 bN = *(const bf16x8*)(bp + 2 * 32 * 64 * 8);
            aR0  = __builtin_amdgcn_mfma_f32_16x16x32_bf16(ha0[kk], bR, aR0, 0, 0, 0);
            aR1  = __builtin_amdgcn_mfma_f32_16x16x32_bf16(ha1[kk], bR, aR1, 0, 0, 0);
            aZ0  = __builtin_amdgcn_mfma_f32_16x16x32_bf16(ha0[kk], bZ, aZ0, 0, 0, 0);
            aZ1  = __builtin_amdgcn_mfma_f32_16x16x32_bf16(ha1[kk], bZ, aZ1, 0, 0, 0);
            aGh0 = __builtin_amdgcn_mfma_f32_16x16x32_bf16(ha0[kk], bN, aGh0, 0, 0, 0);
            aGh1 = __builtin_amdgcn_mfma_f32_16x16x32_bf16(ha1[kk], bN, aGh1, 0, 0, 0);
        }

        // ---- all waves publish partials ----
        *(f32x4*)&red[w][0][lane * 4] = aR0;
        *(f32x4*)&red[w][1][lane * 4] = aR1;
        *(f32x4*)&red[w][2][lane * 4] = aZ0;
        *(f32x4*)&red[w][3][lane * 4] = aZ1;
        *(f32x4*)&red[w][4][lane * 4] = aGh0;
        *(f32x4*)&red[w][5][lane * 4] = aGh1;
        *(f32x4*)&red[w][6][lane * 4] = aGi0;
        *(f32x4*)&red[w][7][lane * 4] = aGi1;
        __syncthreads();

        // ---- 4 gate waves: each reduces + gates ONE mtile ----
        if (gateW) {
            const int s = kq;          // sub-index within mp group (0 or 1)
            f32x4 R  = {0,0,0,0}, Z = {0,0,0,0}, Gh = {0,0,0,0}, Gi = {0,0,0,0};
#pragma unroll
            for (int q = 0; q < 4; q++) {
                const int src = mp * 4 + q;
                R  += *(const f32x4*)&red[src][0 + s][lane * 4];
                Z  += *(const f32x4*)&red[src][2 + s][lane * 4];
                Gh += *(const f32x4*)&red[src][4 + s][lane * 4];
                Gi += *(const f32x4*)&red[src][6 + s][lane * 4];
            }
#pragma unroll
            for (int r = 0; r < 4; r++) {
                const float rr = 1.f / (1.f + __expf(-(R[r] + bir + bhr)));
                const float zz = 1.f / (1.f + __expf(-(Z[r] + biz + bhz)));
                const float nn = tanhf(Gi[r] + bin_ + rr * (Gh[r] + bhn));
                const float hn = (1.f - zz) * nn + zz * hp[r];
                hp[r] = hn;
                const int b = mt * 16 + lhi * 4 + r;
                store_h(&hw[(long)b * HID + jg], f2bf(hn));
            }
        }
#pragma unroll
        for (int kk = 0; kk < 4; kk++) { xa0[kk] = xb0[kk]; xa1[kk] = xb1[kk]; }

        flag_barrier(flags, g, t + 2);
    }

    // ---- epilogue: block-local FC partial over its 16 cols, atomicAdd out ----
    float (*hsl)[JPB] = reinterpret_cast<float(*)[JPB]>(&red[0][0][0]);  // [64][16]
    if (gateW) {
#pragma unroll
        for (int r = 0; r < 4; r++) {
            const int b = mt * 16 + lhi * 4 + r;
            hsl[b][l16] = hp[r];
        }
    }
    __syncthreads();
    if (tid < BATCH * NOUT) {
        const int b = tid / NOUT, o = tid - b * NOUT;
        float acc = (g == 0) ? fc_b[o] : 0.0f;
#pragma unroll
        for (int jl = 0; jl < JPB; jl++)
            acc += hsl[b][jl] * fc_W[(g * JPB + jl) * NOUT + o];
        atomicAdd(&out[tid], acc);
    }
}

// ---------------------------------------------------------------------------
extern "C" void kernel_launch(void* const* d_in, const int* in_sizes, int n_in,
                              void* d_out, int out_size, void* d_ws, size_t ws_size,
                              hipStream_t stream) {
    const int*   text = (const int*)  d_in[0];
    const float* emb  = (const float*)d_in[1];
    const float* W_ih = (const float*)d_in[2];
    const float* W_hh = (const float*)d_in[3];
    const float* b_ih = (const float*)d_in[4];
    const float* b_hh = (const float*)d_in[5];
    const float* fc_W = (const float*)d_in[6];
    const float* fc_b = (const float*)d_in[7];
    float* out = (float*)d_out;

    // ws layout (bytes):
    //   flags [64*16] int                          : 4096
    //   hbuf  [2][64][1024] bf16                   : 262144
    //   whh_f [64][3][32][64][8] bf16              : 6291456
    //   wih_f [64][3][16][64][8] bf16              : 3145728
    char* ws = (char*)d_ws;
    int*            flags = (int*)(ws);
    unsigned short* hbuf  = (unsigned short*)(ws + 4096);
    unsigned short* whh_f = (unsigned short*)(ws + 4096 + 262144);
    unsigned short* wih_f = (unsigned short*)(ws + 4096 + 262144 + 6291456);

    hipMemsetAsync(flags, 0, 4096, stream);
    hipMemsetAsync(out, 0, (size_t)out_size * sizeof(float), stream);

    const long nfrag_hh = (long)NBLK * 3 * 32 * 64;   // 393216
    const long nfrag_ih = (long)NBLK * 3 * 16 * 64;   // 196608
    pack_w<<<(int)((nfrag_hh + 255) / 256), 256, 0, stream>>>(W_hh, whh_f, HID);
    pack_w<<<(int)((nfrag_ih + 255) / 256), 256, 0, stream>>>(W_ih, wih_f, EMBD);

    void* args[] = { (void*)&text, (void*)&emb, (void*)&b_ih, (void*)&b_hh,
                     (void*)&fc_W, (void*)&fc_b, (void*)&whh_f, (void*)&wih_f,
                     (void*)&hbuf, (void*)&flags, (void*)&out };
    hipLaunchCooperativeKernel((void*)gru_mfma, dim3(NBLK), dim3(NTHR), args, 0, stream);
}

// Round 5
// 5727.859 us; speedup vs baseline: 15.1990x; 1.4384x over previous
//
#include <hip/hip_runtime.h>
#include <hip/hip_cooperative_groups.h>
#include <hip/hip_bf16.h>
#include <math.h>

constexpr int EMBD  = 512;
constexpr int HID   = 1024;
constexpr int NOUT  = 5;
constexpr int SEQ   = 512;
constexpr int BATCH = 64;

constexpr int NBLK = 64;    // cooperative blocks; block owns 16 hidden cols
constexpr int NTHR = 512;   // 8 waves: (mp in 0..1) x (kq in 0..3)
constexpr int JPB  = 16;    // hidden cols per block

typedef __attribute__((ext_vector_type(8))) short bf16x8;
typedef __attribute__((ext_vector_type(4))) float f32x4;

__device__ inline unsigned short f2bf(float f) {
    __hip_bfloat16 h = __float2bfloat16(f);
    return *reinterpret_cast<unsigned short*>(&h);
}

__device__ inline bf16x8 cvt8v(f32x4 a, f32x4 b) {
    bf16x8 r;
#pragma unroll
    for (int i = 0; i < 4; i++) { __hip_bfloat16 h = __float2bfloat16(a[i]); r[i]     = *reinterpret_cast<short*>(&h); }
#pragma unroll
    for (int i = 0; i < 4; i++) { __hip_bfloat16 h = __float2bfloat16(b[i]); r[4 + i] = *reinterpret_cast<short*>(&h); }
    return r;
}

// Agent-scope (LLC-coherent) h exchange: bypasses possibly-stale L1/L2.
__device__ inline bf16x8 load_h16(const unsigned short* p) {
    unsigned long long lo = __hip_atomic_load((const unsigned long long*)p,
                              __ATOMIC_RELAXED, __HIP_MEMORY_SCOPE_AGENT);
    unsigned long long hi = __hip_atomic_load(((const unsigned long long*)p) + 1,
                              __ATOMIC_RELAXED, __HIP_MEMORY_SCOPE_AGENT);
    union { unsigned long long u[2]; bf16x8 v; } r;
    r.u[0] = lo; r.u[1] = hi;
    return r.v;
}

__device__ inline void store_h(unsigned short* p, unsigned short v) {
    __hip_atomic_store(p, v, __ATOMIC_RELAXED, __HIP_MEMORY_SCOPE_AGENT);
}

// Split-phase distributed-flag barrier (no RMW).
// arrive: (gate waves drain their h stores) -> block sync -> tid0 stores
//         flags[g]=ep (fire-and-forget). Flags packed: 64 ints = 4 lines.
// wait:   ONLY wave 0 polls all 64 flags (one 64-lane load, 4 line reqs)
//         with s_sleep backoff; block sync releases everyone.
// Work placed between arrive and wait runs in the barrier shadow.
__device__ inline void bar_arrive(int* flags, int g, int ep, bool drain) {
    if (drain) asm volatile("s_waitcnt vmcnt(0)" ::: "memory");
    __syncthreads();
    if (threadIdx.x == 0)
        __hip_atomic_store(&flags[g], ep, __ATOMIC_RELAXED, __HIP_MEMORY_SCOPE_AGENT);
}

__device__ inline void bar_wait(int* flags, int ep) {
    if (threadIdx.x < 64) {
        int f = __hip_atomic_load(&flags[threadIdx.x],
                                  __ATOMIC_RELAXED, __HIP_MEMORY_SCOPE_AGENT);
        while (__any(f < ep)) {
            __builtin_amdgcn_s_sleep(4);
            f = __hip_atomic_load(&flags[threadIdx.x],
                                  __ATOMIC_RELAXED, __HIP_MEMORY_SCOPE_AGENT);
        }
    }
    __syncthreads();
}

// ---------------------------------------------------------------------------
// Pack W [K, 3072] fp32 -> bf16 MFMA B-fragments, layout [g][nt][kt][lane][8]
// ---------------------------------------------------------------------------
__global__ __launch_bounds__(256) void pack_w(const float* __restrict__ W,
                                              unsigned short* __restrict__ out,
                                              int K) {
    const int nkt = K / 32;
    long idx = (long)blockIdx.x * 256 + threadIdx.x;
    const long total = (long)NBLK * 3 * nkt * 64;
    if (idx >= total) return;
    const int lane = idx & 63;
    long rest = idx >> 6;
    const int kt = rest % nkt; rest /= nkt;
    const int nt = rest % 3;
    const int g  = rest / 3;
    const int k0  = kt * 32 + (lane >> 4) * 8;
    const int col = nt * HID + g * JPB + (lane & 15);
    unsigned short* o = out + idx * 8;
#pragma unroll
    for (int i = 0; i < 8; i++)
        o[i] = f2bf(W[(long)(k0 + i) * 3072 + col]);
}

// ---------------------------------------------------------------------------
// One-shot embedding: xall[t*BATCH+b][e] = bf16(emb[text[t][b]][e]).
// Removes the per-step random HBM gather from the recurrent loop.
// ---------------------------------------------------------------------------
__global__ __launch_bounds__(256) void embed_x(const int* __restrict__ text,
                                               const float* __restrict__ emb,
                                               unsigned short* __restrict__ xall) {
    long idx = (long)blockIdx.x * 256 + threadIdx.x;   // (row, chunk-of-8)
    const int row = (int)(idx >> 6);
    if (row >= SEQ * BATCH) return;
    const int e0 = (int)(idx & 63) * 8;
    const int tok = text[row];
    const float* s = emb + (long)tok * EMBD + e0;
    *(bf16x8*)(xall + (long)row * EMBD + e0) =
        cvt8v(*(const f32x4*)s, *(const f32x4*)(s + 4));
}

// ---------------------------------------------------------------------------
// Persistent GRU: 64 blocks x 512 threads, split-phase flag barrier per step.
// Wave w = (mp = w>>2, kq = w&3). MFMA: wave owns m-tiles {2mp,2mp+1},
// K-quarter kq. Gate phase: waves with kq<2 each own one mtile mp*2+kq.
// x_{t+1} prefetched in the barrier shadow (between arrive and wait).
// ---------------------------------------------------------------------------
__global__ void __launch_bounds__(NTHR, 2) gru_mfma(
    const unsigned short* __restrict__ xall,   // [SEQ*BATCH][EMBD] bf16
    const float*          __restrict__ b_ih,   // [3072]
    const float*          __restrict__ b_hh,   // [3072]
    const float*          __restrict__ fc_W,   // [HID][NOUT]
    const float*          __restrict__ fc_b,   // [NOUT]
    const unsigned short* __restrict__ whh_f,  // [64][3][32][64][8]
    const unsigned short* __restrict__ wih_f,  // [64][3][16][64][8]
    unsigned short*       __restrict__ hbuf,   // [2][BATCH][HID] bf16
    int*                  __restrict__ flags,  // [64] (zeroed)
    float*                __restrict__ out)    // [BATCH][NOUT] (zeroed)
{
    const int g    = blockIdx.x;
    const int tid  = threadIdx.x;
    const int lane = tid & 63;
    const int w    = tid >> 6;
    const int mp   = w >> 2;   // 0..1
    const int kq   = w & 3;    // 0..3
    const int l16  = lane & 15;
    const int lhi  = lane >> 4;

    __shared__ float red[8][8][256];   // [wave][tile][lane*4+r] = 64 KB

    const int rowA0 = (mp * 2 + 0) * 16 + l16;   // A-frag rows (b indices)
    const int rowA1 = (mp * 2 + 1) * 16 + l16;

    // zero h buffer 0 (this block's 16-col slice, all b) via LLC stores
    for (int i = tid; i < BATCH * JPB; i += NTHR) {
        const int b = i >> 4, jl = i & 15;
        store_h(&hbuf[(long)b * HID + g * JPB + jl], 0);
    }

    // biases for this lane's j (used by gate waves)
    const int jg = g * JPB + l16;
    const float bir  = b_ih[jg],           bhr = b_hh[jg];
    const float biz  = b_ih[HID + jg],     bhz = b_hh[HID + jg];
    const float bin_ = b_ih[2 * HID + jg], bhn = b_hh[2 * HID + jg];

    const bool gateW = (kq < 2);
    const int  mt    = mp * 2 + kq;          // gate wave's mtile (kq<2 only)
    float hp[4] = {0.f, 0.f, 0.f, 0.f};      // fp32 carry (gate waves)

    bf16x8 xa0[4], xa1[4];

    auto loadX = [&](int t) {
        const unsigned short* x0 = xall + ((long)t * BATCH + rowA0) * EMBD;
        const unsigned short* x1 = xall + ((long)t * BATCH + rowA1) * EMBD;
#pragma unroll
        for (int kk = 0; kk < 4; kk++) {
            const int k0 = (kq * 4 + kk) * 32 + lhi * 8;
            xa0[kk] = *(const bf16x8*)(x0 + k0);
            xa1[kk] = *(const bf16x8*)(x1 + k0);
        }
    };

    const unsigned short* whh_g = whh_f + (long)g * 3 * 32 * 64 * 8;
    const unsigned short* wih_g = wih_f + (long)g * 3 * 16 * 64 * 8;

    bar_arrive(flags, g, 1, true);   // h0 zero stores drained
    loadX(0);                        // x_0 prefetch in barrier shadow
    bar_wait(flags, 1);

    for (int t = 0; t < SEQ; ++t) {
        const unsigned short* hr = hbuf + (long)(t & 1) * BATCH * HID;
        unsigned short*       hw = hbuf + (long)((t + 1) & 1) * BATCH * HID;

        // ---- issue ALL h-fragment loads first (LLC latency hides under gi) ----
        bf16x8 ha0[8], ha1[8];
#pragma unroll
        for (int kk = 0; kk < 8; kk++) {
            const int k0 = (kq * 8 + kk) * 32 + lhi * 8;
            ha0[kk] = load_h16(hr + (long)rowA0 * HID + k0);
            ha1[kk] = load_h16(hr + (long)rowA1 * HID + k0);
        }

        f32x4 aR0 = {0,0,0,0}, aR1 = {0,0,0,0};
        f32x4 aZ0 = {0,0,0,0}, aZ1 = {0,0,0,0};
        f32x4 aGh0 = {0,0,0,0}, aGh1 = {0,0,0,0};
        f32x4 aGi0 = {0,0,0,0}, aGi1 = {0,0,0,0};

        // ---- gi: x_t @ W_ih (this wave's K-quarter: 4 ktiles) ----
#pragma unroll
        for (int kk = 0; kk < 4; kk++) {
            const unsigned short* bp = wih_g + (((long)(kq * 4 + kk)) * 64 + lane) * 8;
            const bf16x8 bR = *(const bf16x8*)(bp);
            const bf16x8 bZ = *(const bf16x8*)(bp + 16 * 64 * 8);
            const bf16x8 bN = *(const bf16x8*)(bp + 2 * 16 * 64 * 8);
            aR0  = __builtin_amdgcn_mfma_f32_16x16x32_bf16(xa0[kk], bR, aR0, 0, 0, 0);
            aR1  = __builtin_amdgcn_mfma_f32_16x16x32_bf16(xa1[kk], bR, aR1, 0, 0, 0);
            aZ0  = __builtin_amdgcn_mfma_f32_16x16x32_bf16(xa0[kk], bZ, aZ0, 0, 0, 0);
            aZ1  = __builtin_amdgcn_mfma_f32_16x16x32_bf16(xa1[kk], bZ, aZ1, 0, 0, 0);
            aGi0 = __builtin_amdgcn_mfma_f32_16x16x32_bf16(xa0[kk], bN, aGi0, 0, 0, 0);
            aGi1 = __builtin_amdgcn_mfma_f32_16x16x32_bf16(xa1[kk], bN, aGi1, 0, 0, 0);
        }

        // ---- gh: h_t @ W_hh (this wave's K-quarter: 8 ktiles) ----
#pragma unroll
        for (int kk = 0; kk < 8; kk++) {
            const int kt = kq * 8 + kk;
            const unsigned short* bp = whh_g + (((long)kt) * 64 + lane) * 8;
            const bf16x8 bR = *(const bf16x8*)(bp);
            const bf16x8 bZ = *(const bf16x8*)(bp + 32 * 64 * 8);
            const bf16x8 bN = *(const bf16x8*)(bp + 2 * 32 * 64 * 8);
            aR0  = __builtin_amdgcn_mfma_f32_16x16x32_bf16(ha0[kk], bR, aR0, 0, 0, 0);
            aR1  = __builtin_amdgcn_mfma_f32_16x16x32_bf16(ha1[kk], bR, aR1, 0, 0, 0);
            aZ0  = __builtin_amdgcn_mfma_f32_16x16x32_bf16(ha0[kk], bZ, aZ0, 0, 0, 0);
            aZ1  = __builtin_amdgcn_mfma_f32_16x16x32_bf16(ha1[kk], bZ, aZ1, 0, 0, 0);
            aGh0 = __builtin_amdgcn_mfma_f32_16x16x32_bf16(ha0[kk], bN, aGh0, 0, 0, 0);
            aGh1 = __builtin_amdgcn_mfma_f32_16x16x32_bf16(ha1[kk], bN, aGh1, 0, 0, 0);
        }

        // ---- all waves publish partials ----
        *(f32x4*)&red[w][0][lane * 4] = aR0;
        *(f32x4*)&red[w][1][lane * 4] = aR1;
        *(f32x4*)&red[w][2][lane * 4] = aZ0;
        *(f32x4*)&red[w][3][lane * 4] = aZ1;
        *(f32x4*)&red[w][4][lane * 4] = aGh0;
        *(f32x4*)&red[w][5][lane * 4] = aGh1;
        *(f32x4*)&red[w][6][lane * 4] = aGi0;
        *(f32x4*)&red[w][7][lane * 4] = aGi1;
        __syncthreads();

        // ---- 4 gate waves: each reduces + gates ONE mtile ----
        if (gateW) {
            const int s = kq;          // sub-index within mp group (0 or 1)
            f32x4 R  = {0,0,0,0}, Z = {0,0,0,0}, Gh = {0,0,0,0}, Gi = {0,0,0,0};
#pragma unroll
            for (int q = 0; q < 4; q++) {
                const int src = mp * 4 + q;
                R  += *(const f32x4*)&red[src][0 + s][lane * 4];
                Z  += *(const f32x4*)&red[src][2 + s][lane * 4];
                Gh += *(const f32x4*)&red[src][4 + s][lane * 4];
                Gi += *(const f32x4*)&red[src][6 + s][lane * 4];
            }
#pragma unroll
            for (int r = 0; r < 4; r++) {
                const float rr = 1.f / (1.f + __expf(-(R[r] + bir + bhr)));
                const float zz = 1.f / (1.f + __expf(-(Z[r] + biz + bhz)));
                const float nn = tanhf(Gi[r] + bin_ + rr * (Gh[r] + bhn));
                const float hn = (1.f - zz) * nn + zz * hp[r];
                hp[r] = hn;
                const int b = mt * 16 + lhi * 4 + r;
                store_h(&hw[(long)b * HID + jg], f2bf(hn));
            }
        }

        // ---- barrier: arrive (gate waves drain h stores), prefetch x_{t+1}
        //      in the shadow, then wait ----
        bar_arrive(flags, g, t + 2, gateW);
        loadX((t + 1 < SEQ) ? t + 1 : SEQ - 1);
        bar_wait(flags, t + 2);
    }

    // ---- epilogue: block-local FC partial over its 16 cols, atomicAdd out ----
    float (*hsl)[JPB] = reinterpret_cast<float(*)[JPB]>(&red[0][0][0]);  // [64][16]
    if (gateW) {
#pragma unroll
        for (int r = 0; r < 4; r++) {
            const int b = mt * 16 + lhi * 4 + r;
            hsl[b][l16] = hp[r];
        }
    }
    __syncthreads();
    if (tid < BATCH * NOUT) {
        const int b = tid / NOUT, o = tid - b * NOUT;
        float acc = (g == 0) ? fc_b[o] : 0.0f;
#pragma unroll
        for (int jl = 0; jl < JPB; jl++)
            acc += hsl[b][jl] * fc_W[(g * JPB + jl) * NOUT + o];
        atomicAdd(&out[tid], acc);
    }
}

// ---------------------------------------------------------------------------
extern "C" void kernel_launch(void* const* d_in, const int* in_sizes, int n_in,
                              void* d_out, int out_size, void* d_ws, size_t ws_size,
                              hipStream_t stream) {
    const int*   text = (const int*)  d_in[0];
    const float* emb  = (const float*)d_in[1];
    const float* W_ih = (const float*)d_in[2];
    const float* W_hh = (const float*)d_in[3];
    const float* b_ih = (const float*)d_in[4];
    const float* b_hh = (const float*)d_in[5];
    const float* fc_W = (const float*)d_in[6];
    const float* fc_b = (const float*)d_in[7];
    float* out = (float*)d_out;

    // ws layout (bytes):
    //   flags [64] int (rounded to 4096)           : 4096
    //   hbuf  [2][64][1024] bf16                   : 262144
    //   whh_f [64][3][32][64][8] bf16              : 6291456
    //   wih_f [64][3][16][64][8] bf16              : 3145728
    //   xall  [512*64][512] bf16                   : 33554432   (~43.3 MB total)
    char* ws = (char*)d_ws;
    int*            flags = (int*)(ws);
    unsigned short* hbuf  = (unsigned short*)(ws + 4096);
    unsigned short* whh_f = (unsigned short*)(ws + 4096 + 262144);
    unsigned short* wih_f = (unsigned short*)(ws + 4096 + 262144 + 6291456);
    unsigned short* xall  = (unsigned short*)(ws + 4096 + 262144 + 6291456 + 3145728);

    hipMemsetAsync(flags, 0, 4096, stream);
    hipMemsetAsync(out, 0, (size_t)out_size * sizeof(float), stream);

    const long nfrag_hh = (long)NBLK * 3 * 32 * 64;   // 393216
    const long nfrag_ih = (long)NBLK * 3 * 16 * 64;   // 196608
    pack_w<<<(int)((nfrag_hh + 255) / 256), 256, 0, stream>>>(W_hh, whh_f, HID);
    pack_w<<<(int)((nfrag_ih + 255) / 256), 256, 0, stream>>>(W_ih, wih_f, EMBD);

    const long nx = (long)SEQ * BATCH * 64;           // threads for embed_x
    embed_x<<<(int)((nx + 255) / 256), 256, 0, stream>>>(text, emb, xall);

    void* args[] = { (void*)&xall, (void*)&b_ih, (void*)&b_hh,
                     (void*)&fc_W, (void*)&fc_b, (void*)&whh_f, (void*)&wih_f,
                     (void*)&hbuf, (void*)&flags, (void*)&out };
    hipLaunchCooperativeKernel((void*)gru_mfma, dim3(NBLK), dim3(NTHR), args, 0, stream);
}

// Round 7
// 3041.273 us; speedup vs baseline: 28.6254x; 1.8834x over previous
//
#include <hip/hip_runtime.h>
#include <hip/hip_cooperative_groups.h>
#include <hip/hip_bf16.h>
#include <math.h>

constexpr int EMBD  = 512;
constexpr int HID   = 1024;
constexpr int NOUT  = 5;
constexpr int SEQ   = 512;
constexpr int BATCH = 64;

constexpr int NBLK = 64;    // cooperative blocks; block owns 16 hidden cols
constexpr int NTHR = 512;   // 8 waves: (mp in 0..1) x (kq in 0..3)
constexpr int JPB  = 16;    // hidden cols per block

typedef __attribute__((ext_vector_type(8))) short bf16x8;
typedef __attribute__((ext_vector_type(4))) float f32x4;

__device__ inline unsigned short f2bf(float f) {
    __hip_bfloat16 h = __float2bfloat16(f);
    return *reinterpret_cast<unsigned short*>(&h);
}

__device__ inline bf16x8 cvt8v(f32x4 a, f32x4 b) {
    bf16x8 r;
#pragma unroll
    for (int i = 0; i < 4; i++) { __hip_bfloat16 h = __float2bfloat16(a[i]); r[i]     = *reinterpret_cast<short*>(&h); }
#pragma unroll
    for (int i = 0; i < 4; i++) { __hip_bfloat16 h = __float2bfloat16(b[i]); r[4 + i] = *reinterpret_cast<short*>(&h); }
    return r;
}

// Agent-scope (MALL-coherent) 8B ops for the h exchange.
__device__ inline unsigned long long load_a8(const unsigned short* p) {
    return __hip_atomic_load((const unsigned long long*)p,
                             __ATOMIC_RELAXED, __HIP_MEMORY_SCOPE_AGENT);
}
__device__ inline void store_a8(unsigned short* p, unsigned long long v) {
    __hip_atomic_store((unsigned long long*)p, v,
                       __ATOMIC_RELAXED, __HIP_MEMORY_SCOPE_AGENT);
}
// 16B fragment load = two 8B agent loads (coalesced: lane-contiguous layout).
__device__ inline bf16x8 load_frag(const unsigned short* p) {
    union { unsigned long long u[2]; bf16x8 v; } r;
    r.u[0] = load_a8(p);
    r.u[1] = load_a8(p + 4);
    return r.v;
}

__device__ inline float sigm(float x) { return 1.f / (1.f + __expf(-x)); }
__device__ inline float ftanh(float x) { return 1.f - 2.f / (1.f + __expf(2.f * x)); }

// ---------------------------------------------------------------------------
// Pack W [K, 3072] fp32 -> bf16 MFMA B-fragments, layout [g][nt][kt][lane][8]
// ---------------------------------------------------------------------------
__global__ __launch_bounds__(256) void pack_w(const float* __restrict__ W,
                                              unsigned short* __restrict__ out,
                                              int K) {
    const int nkt = K / 32;
    long idx = (long)blockIdx.x * 256 + threadIdx.x;
    const long total = (long)NBLK * 3 * nkt * 64;
    if (idx >= total) return;
    const int lane = idx & 63;
    long rest = idx >> 6;
    const int kt = rest % nkt; rest /= nkt;
    const int nt = rest % 3;
    const int g  = rest / 3;
    const int k0  = kt * 32 + (lane >> 4) * 8;
    const int col = nt * HID + g * JPB + (lane & 15);
    unsigned short* o = out + idx * 8;
#pragma unroll
    for (int i = 0; i < 8; i++)
        o[i] = f2bf(W[(long)(k0 + i) * 3072 + col]);
}

// ---------------------------------------------------------------------------
// One-shot embedding into A-FRAGMENT layout:
// xfrag[t][bt(4)][kt(16)][lane(64)][8]: value = x_t[bt*16+(lane&15)]
//                                               [kt*32+(lane>>4)*8+i]
// ---------------------------------------------------------------------------
__global__ __launch_bounds__(256) void embed_x(const int* __restrict__ text,
                                               const float* __restrict__ emb,
                                               unsigned short* __restrict__ xfrag) {
    long idx = (long)blockIdx.x * 256 + threadIdx.x;
    if (idx >= (long)SEQ * 4 * 16 * 64) return;
    const int lane = idx & 63;
    const int kt   = (idx >> 6) & 15;
    const int bt   = (idx >> 10) & 3;
    const int t    = (int)(idx >> 12);
    const int b    = bt * 16 + (lane & 15);
    const int e0   = kt * 32 + (lane >> 4) * 8;
    const int tok  = text[t * BATCH + b];
    const float* s = emb + (long)tok * EMBD + e0;
    *(bf16x8*)(xfrag + idx * 8) = cvt8v(*(const f32x4*)s, *(const f32x4*)(s + 4));
}

// ---------------------------------------------------------------------------
// Persistent GRU: 64 blocks x 512 threads. h lives in fragment layout
// hfrag[buf][bt(4)][kt(32)][lane(64)][8] bf16 -> all h loads/stores are
// lane-contiguous full-line transactions. Per-step pipeline:
//   MFMA -> red(LDS) -> sync -> gate waves (kq<2) reduce+gate+hx(LDS)
//   -> sync -> storer waves (kq>=2) emit h' frags (8B agent stores)+drain
//   -> sync -> flag arrive; loadX(t+1) in shadow; wave0 polls -> sync
// ---------------------------------------------------------------------------
__global__ void __launch_bounds__(NTHR, 2) gru_mfma(
    const unsigned short* __restrict__ xfrag,  // [SEQ][4][16][64][8] bf16
    const float*          __restrict__ b_ih,   // [3072]
    const float*          __restrict__ b_hh,   // [3072]
    const float*          __restrict__ fc_W,   // [HID][NOUT]
    const float*          __restrict__ fc_b,   // [NOUT]
    const unsigned short* __restrict__ whh_f,  // [64][3][32][64][8]
    const unsigned short* __restrict__ wih_f,  // [64][3][16][64][8]
    unsigned short*       __restrict__ hbuf,   // [2][4][32][64][8] bf16
    int*                  __restrict__ flags,  // [64] (zeroed)
    float*                __restrict__ out)    // [BATCH][NOUT] (zeroed)
{
    const int g    = blockIdx.x;
    const int tid  = threadIdx.x;
    const int lane = tid & 63;
    const int w    = tid >> 6;
    const int mp   = w >> 2;   // 0..1
    const int kq   = w & 3;    // 0..3
    const int l16  = lane & 15;
    const int lhi  = lane >> 4;

    __shared__ float red[8][8][256];            // 64 KB partial buffer
    __shared__ unsigned short hx[64][16];       // 2 KB h' transpose buffer

    constexpr int HFRAG = 4 * 32 * 64 * 8;      // ushorts per h buffer (64K)

    // zero BOTH h buffers: 2*HFRAG ushorts = 32768 ull slots total,
    // 512 ull per block (R6 bug: 1024 overran into whh_f and zeroed weights)
    for (int i = tid; i < 512; i += NTHR)
        store_a8(hbuf + ((long)g * 512 + i) * 4, 0ull);

    // biases for this lane's j (used by gate waves)
    const int jg = g * JPB + l16;
    const float bir  = b_ih[jg],           bhr = b_hh[jg];
    const float biz  = b_ih[HID + jg],     bhz = b_hh[HID + jg];
    const float bin_ = b_ih[2 * HID + jg], bhn = b_hh[2 * HID + jg];

    const bool gateW  = (kq < 2);
    const bool storeW = (kq >= 2);
    const int  mtG    = mp * 2 + kq;         // gate wave's btile (kq<2)
    const int  mtS    = mp * 2 + (kq - 2);   // storer wave's btile (kq>=2)
    float hp[4] = {0.f, 0.f, 0.f, 0.f};      // fp32 carry (gate waves)

    bf16x8 xa0[4], xa1[4];
    auto loadX = [&](int t) {
        const unsigned short* base = xfrag + (long)t * (4 * 16 * 64 * 8);
#pragma unroll
        for (int kk = 0; kk < 4; kk++) {
            const int kt = kq * 4 + kk;
            xa0[kk] = *(const bf16x8*)(base + (((2 * mp + 0) * 16 + kt) * 64 + lane) * 8);
            xa1[kk] = *(const bf16x8*)(base + (((2 * mp + 1) * 16 + kt) * 64 + lane) * 8);
        }
    };

    // storer-wave addressing: lane s covers consumer-lane cl = s>>1, half s&1
    const int sb  = mtS * 16 + ((lane >> 1) & 15);              // source b row
    const int sjl = ((lane >> 1) >> 4) * 8 + 4 * (lane & 1);    // source j-local
    // dst offset (ushorts) within a buffer, at btile mtS, ktile g>>1:
    const long sdst = (((long)mtS * 32 + (g >> 1)) * 64) * 8 + 256 * (g & 1) + lane * 4;

    const unsigned short* whh_g = whh_f + (long)g * 3 * 32 * 64 * 8;
    const unsigned short* wih_g = wih_f + (long)g * 3 * 16 * 64 * 8;

    // ---- init barrier ----
    asm volatile("s_waitcnt vmcnt(0)" ::: "memory");
    __syncthreads();
    if (tid == 0)
        __hip_atomic_store(&flags[g], 1, __ATOMIC_RELAXED, __HIP_MEMORY_SCOPE_AGENT);
    loadX(0);
    if (tid < 64) {
        int f = __hip_atomic_load(&flags[tid], __ATOMIC_RELAXED, __HIP_MEMORY_SCOPE_AGENT);
        while (__any(f < 1)) {
            __builtin_amdgcn_s_sleep(2);
            f = __hip_atomic_load(&flags[tid], __ATOMIC_RELAXED, __HIP_MEMORY_SCOPE_AGENT);
        }
    }
    __syncthreads();

    for (int t = 0; t < SEQ; ++t) {
        const unsigned short* hr = hbuf + (long)(t & 1) * HFRAG;
        unsigned short*       hw = hbuf + (long)((t + 1) & 1) * HFRAG;

        // ---- h fragment loads: lane-contiguous, coalesced; latency partly
        //      hidden under gi MFMAs ----
        bf16x8 ha0[8], ha1[8];
#pragma unroll
        for (int kk = 0; kk < 8; kk++) {
            const int kt = kq * 8 + kk;
            ha0[kk] = load_frag(hr + (((long)(2 * mp + 0) * 32 + kt) * 64 + lane) * 8);
            ha1[kk] = load_frag(hr + (((long)(2 * mp + 1) * 32 + kt) * 64 + lane) * 8);
        }

        f32x4 aR0 = {0,0,0,0}, aR1 = {0,0,0,0};
        f32x4 aZ0 = {0,0,0,0}, aZ1 = {0,0,0,0};
        f32x4 aGh0 = {0,0,0,0}, aGh1 = {0,0,0,0};
        f32x4 aGi0 = {0,0,0,0}, aGi1 = {0,0,0,0};

        // ---- gi: x_t @ W_ih ----
#pragma unroll
        for (int kk = 0; kk < 4; kk++) {
            const unsigned short* bp = wih_g + (((long)(kq * 4 + kk)) * 64 + lane) * 8;
            const bf16x8 bR = *(const bf16x8*)(bp);
            const bf16x8 bZ = *(const bf16x8*)(bp + 16 * 64 * 8);
            const bf16x8 bN = *(const bf16x8*)(bp + 2 * 16 * 64 * 8);
            aR0  = __builtin_amdgcn_mfma_f32_16x16x32_bf16(xa0[kk], bR, aR0, 0, 0, 0);
            aR1  = __builtin_amdgcn_mfma_f32_16x16x32_bf16(xa1[kk], bR, aR1, 0, 0, 0);
            aZ0  = __builtin_amdgcn_mfma_f32_16x16x32_bf16(xa0[kk], bZ, aZ0, 0, 0, 0);
            aZ1  = __builtin_amdgcn_mfma_f32_16x16x32_bf16(xa1[kk], bZ, aZ1, 0, 0, 0);
            aGi0 = __builtin_amdgcn_mfma_f32_16x16x32_bf16(xa0[kk], bN, aGi0, 0, 0, 0);
            aGi1 = __builtin_amdgcn_mfma_f32_16x16x32_bf16(xa1[kk], bN, aGi1, 0, 0, 0);
        }

        // ---- gh: h_t @ W_hh ----
#pragma unroll
        for (int kk = 0; kk < 8; kk++) {
            const int kt = kq * 8 + kk;
            const unsigned short* bp = whh_g + (((long)kt) * 64 + lane) * 8;
            const bf16x8 bR = *(const bf16x8*)(bp);
            const bf16x8 bZ = *(const bf16x8*)(bp + 32 * 64 * 8);
            const bf16x8 bN = *(const bf16x8*)(bp + 2 * 32 * 64 * 8);
            aR0  = __builtin_amdgcn_mfma_f32_16x16x32_bf16(ha0[kk], bR, aR0, 0, 0, 0);
            aR1  = __builtin_amdgcn_mfma_f32_16x16x32_bf16(ha1[kk], bR, aR1, 0, 0, 0);
            aZ0  = __builtin_amdgcn_mfma_f32_16x16x32_bf16(ha0[kk], bZ, aZ0, 0, 0, 0);
            aZ1  = __builtin_amdgcn_mfma_f32_16x16x32_bf16(ha1[kk], bZ, aZ1, 0, 0, 0);
            aGh0 = __builtin_amdgcn_mfma_f32_16x16x32_bf16(ha0[kk], bN, aGh0, 0, 0, 0);
            aGh1 = __builtin_amdgcn_mfma_f32_16x16x32_bf16(ha1[kk], bN, aGh1, 0, 0, 0);
        }

        // ---- publish partials ----
        *(f32x4*)&red[w][0][lane * 4] = aR0;
        *(f32x4*)&red[w][1][lane * 4] = aR1;
        *(f32x4*)&red[w][2][lane * 4] = aZ0;
        *(f32x4*)&red[w][3][lane * 4] = aZ1;
        *(f32x4*)&red[w][4][lane * 4] = aGh0;
        *(f32x4*)&red[w][5][lane * 4] = aGh1;
        *(f32x4*)&red[w][6][lane * 4] = aGi0;
        *(f32x4*)&red[w][7][lane * 4] = aGi1;
        __syncthreads();

        // ---- gate waves: reduce one btile, gates, carry, write hx ----
        if (gateW) {
            const int s = kq;
            f32x4 R  = {0,0,0,0}, Z = {0,0,0,0}, Gh = {0,0,0,0}, Gi = {0,0,0,0};
#pragma unroll
            for (int q = 0; q < 4; q++) {
                const int src = mp * 4 + q;
                R  += *(const f32x4*)&red[src][0 + s][lane * 4];
                Z  += *(const f32x4*)&red[src][2 + s][lane * 4];
                Gh += *(const f32x4*)&red[src][4 + s][lane * 4];
                Gi += *(const f32x4*)&red[src][6 + s][lane * 4];
            }
#pragma unroll
            for (int r = 0; r < 4; r++) {
                const float rr = sigm(R[r] + bir + bhr);
                const float zz = sigm(Z[r] + biz + bhz);
                const float nn = ftanh(Gi[r] + bin_ + rr * (Gh[r] + bhn));
                const float hn = (1.f - zz) * nn + zz * hp[r];
                hp[r] = hn;
                hx[mtG * 16 + lhi * 4 + r][l16] = f2bf(hn);
            }
        }
        __syncthreads();

        // ---- storer waves: emit h' fragments (512B contiguous per btile) ----
        if (storeW) {
            const unsigned long long v =
                *(const unsigned long long*)&hx[sb][sjl];
            store_a8(hw + sdst, v);
            asm volatile("s_waitcnt vmcnt(0)" ::: "memory");
        }
        __syncthreads();

        // ---- flag arrive; x prefetch in shadow; poll; release ----
        if (tid == 0)
            __hip_atomic_store(&flags[g], t + 2, __ATOMIC_RELAXED, __HIP_MEMORY_SCOPE_AGENT);
        loadX((t + 1 < SEQ) ? t + 1 : SEQ - 1);
        if (tid < 64) {
            int f = __hip_atomic_load(&flags[tid], __ATOMIC_RELAXED, __HIP_MEMORY_SCOPE_AGENT);
            while (__any(f < t + 2)) {
                __builtin_amdgcn_s_sleep(2);
                f = __hip_atomic_load(&flags[tid], __ATOMIC_RELAXED, __HIP_MEMORY_SCOPE_AGENT);
            }
        }
        __syncthreads();
    }

    // ---- epilogue: block-local FC partial over its 16 cols, atomicAdd out ----
    float (*hsl)[JPB] = reinterpret_cast<float(*)[JPB]>(&red[0][0][0]);  // [64][16]
    if (gateW) {
#pragma unroll
        for (int r = 0; r < 4; r++) {
            const int b = mtG * 16 + lhi * 4 + r;
            hsl[b][l16] = hp[r];
        }
    }
    __syncthreads();
    if (tid < BATCH * NOUT) {
        const int b = tid / NOUT, o = tid - b * NOUT;
        float acc = (g == 0) ? fc_b[o] : 0.0f;
#pragma unroll
        for (int jl = 0; jl < JPB; jl++)
            acc += hsl[b][jl] * fc_W[(g * JPB + jl) * NOUT + o];
        atomicAdd(&out[tid], acc);
    }
}

// ---------------------------------------------------------------------------
extern "C" void kernel_launch(void* const* d_in, const int* in_sizes, int n_in,
                              void* d_out, int out_size, void* d_ws, size_t ws_size,
                              hipStream_t stream) {
    const int*   text = (const int*)  d_in[0];
    const float* emb  = (const float*)d_in[1];
    const float* W_ih = (const float*)d_in[2];
    const float* W_hh = (const float*)d_in[3];
    const float* b_ih = (const float*)d_in[4];
    const float* b_hh = (const float*)d_in[5];
    const float* fc_W = (const float*)d_in[6];
    const float* fc_b = (const float*)d_in[7];
    float* out = (float*)d_out;

    // ws layout (bytes):
    //   flags [64] int (rounded to 4096)           : 4096
    //   hbuf  [2][4][32][64][8] bf16               : 262144
    //   whh_f [64][3][32][64][8] bf16              : 6291456
    //   wih_f [64][3][16][64][8] bf16              : 3145728
    //   xfrag [512][4][16][64][8] bf16             : 33554432   (~43.3 MB)
    char* ws = (char*)d_ws;
    int*            flags = (int*)(ws);
    unsigned short* hbuf  = (unsigned short*)(ws + 4096);
    unsigned short* whh_f = (unsigned short*)(ws + 4096 + 262144);
    unsigned short* wih_f = (unsigned short*)(ws + 4096 + 262144 + 6291456);
    unsigned short* xfrag = (unsigned short*)(ws + 4096 + 262144 + 6291456 + 3145728);

    hipMemsetAsync(flags, 0, 4096, stream);
    hipMemsetAsync(out, 0, (size_t)out_size * sizeof(float), stream);

    const long nfrag_hh = (long)NBLK * 3 * 32 * 64;   // 393216
    const long nfrag_ih = (long)NBLK * 3 * 16 * 64;   // 196608
    pack_w<<<(int)((nfrag_hh + 255) / 256), 256, 0, stream>>>(W_hh, whh_f, HID);
    pack_w<<<(int)((nfrag_ih + 255) / 256), 256, 0, stream>>>(W_ih, wih_f, EMBD);

    const long nx = (long)SEQ * 4 * 16 * 64;
    embed_x<<<(int)((nx + 255) / 256), 256, 0, stream>>>(text, emb, xfrag);

    void* args[] = { (void*)&xfrag, (void*)&b_ih, (void*)&b_hh,
                     (void*)&fc_W, (void*)&fc_b, (void*)&whh_f, (void*)&wih_f,
                     (void*)&hbuf, (void*)&flags, (void*)&out };
    hipLaunchCooperativeKernel((void*)gru_mfma, dim3(NBLK), dim3(NTHR), args, 0, stream);
}